// Round 7
// baseline (541.752 us; speedup 1.0000x reference)
//
#include <hip/hip_runtime.h>
#include <hip/hip_bf16.h>

#define NN 100000
#define F 128
#define C_OUT 14
#define ZP 16
#define SCAN_CHUNK 1024
#define NBLK ((NN + SCAN_CHUNK - 1) / SCAN_CHUNK)   // 98 blocks
#define NPART 8
#define PART_SZ ((NN + NPART - 1) / NPART)          // 12500
#define BIN_BATCH 2048
#define BIN_CAP 640                                  // LDS bucket capacity
#define PCHUNK 1024                                  // place work-queue chunk

typedef __attribute__((ext_vector_type(8))) short v8s;   // 8 bf16 (4 VGPRs)
typedef __attribute__((ext_vector_type(4))) float v4f;   // 4 fp32 acc

// ---------------- bf16 helpers (manual, zero API risk) ----------------------
static __device__ __forceinline__ unsigned short f2bf(float f) {
    unsigned int u = __float_as_uint(f);
    unsigned int r = (u + 0x7fffu + ((u >> 16) & 1u)) >> 16;   // RTN-even
    return (unsigned short)r;
}
static __device__ __forceinline__ unsigned int pack2(float a, float b) {
    return (unsigned int)f2bf(a) | ((unsigned int)f2bf(b) << 16);
}
static __device__ __forceinline__ void unpack2(unsigned int u, float& lo, float& hi) {
    lo = __uint_as_float(u << 16);
    hi = __uint_as_float(u & 0xffff0000u);
}

// ---------------------------------------------------------------------------
// bin: single pass over edges. cnt histogram via atomicAdd whose RETURN is
// the edge's rank within its dst (free dedup of the old hist kernel).
// Entries (src | dloc<<17 impossible: src 17b + dloc 14b + rank 16b -> uint2:
// x = src, y = dloc<<16 | rank) staged in per-partition LDS buckets and
// flushed in coalesced chunks so bucket lines are written once.
// ---------------------------------------------------------------------------
__global__ __launch_bounds__(256) void bin_kernel(
    const int* __restrict__ src, const int* __restrict__ dst,
    int* __restrict__ cnt, uint2* __restrict__ bucket,
    int* __restrict__ bcursor, int BCAP, int E)
{
    __shared__ uint2 bs[NPART][BIN_CAP];   // 40 KB
    __shared__ int bcnt[NPART], bbase[NPART];
    const int t  = threadIdx.x;
    const int e0 = blockIdx.x * BIN_BATCH;
    if (t < NPART) bcnt[t] = 0;
    __syncthreads();
    #pragma unroll
    for (int j = 0; j < 8; ++j) {
        const int e = e0 + j * 256 + t;
        if (e < E) {
            const int d = dst[e];
            const int s = src[e];
            const int rank = atomicAdd(&cnt[d], 1);
            const int part = d / PART_SZ;
            const int dloc = d - part * PART_SZ;
            uint2 ent;
            ent.x = (unsigned)s;
            ent.y = ((unsigned)dloc << 16) | ((unsigned)rank & 0xffffu);
            const int slot = atomicAdd(&bcnt[part], 1);
            if (slot < BIN_CAP) bs[part][slot] = ent;
            else {
                const int p = atomicAdd(&bcursor[part], 1);
                bucket[(size_t)part * BCAP + p] = ent;
            }
        }
    }
    __syncthreads();
    if (t < NPART) {
        const int c = min(bcnt[t], BIN_CAP);
        bbase[t] = atomicAdd(&bcursor[t], c);
        bcnt[t] = c;
    }
    __syncthreads();
    for (int part = 0; part < NPART; ++part) {
        const int c    = bcnt[part];
        const int base = bbase[part];
        for (int i = t; i < c; i += 256)
            bucket[(size_t)part * BCAP + base + i] = bs[part][i];
    }
}

__global__ __launch_bounds__(256) void scan_local_kernel(
    const int* __restrict__ cnt, int* __restrict__ rowptr,
    int* __restrict__ blocksum)
{
    __shared__ int sm[256];
    const int tid  = threadIdx.x;
    const int base = blockIdx.x * SCAN_CHUNK + tid * 4;
    int v0 = (base + 0 < NN) ? cnt[base + 0] : 0;
    int v1 = (base + 1 < NN) ? cnt[base + 1] : 0;
    int v2 = (base + 2 < NN) ? cnt[base + 2] : 0;
    int v3 = (base + 3 < NN) ? cnt[base + 3] : 0;
    const int t = v0 + v1 + v2 + v3;
    sm[tid] = t;
    __syncthreads();
    int acc = t;
    for (int off = 1; off < 256; off <<= 1) {
        int other = (tid >= off) ? sm[tid - off] : 0;
        __syncthreads();
        acc += other;
        sm[tid] = acc;
        __syncthreads();
    }
    const int excl = acc - t;
    if (base + 0 < NN) rowptr[base + 0] = excl;
    if (base + 1 < NN) rowptr[base + 1] = excl + v0;
    if (base + 2 < NN) rowptr[base + 2] = excl + v0 + v1;
    if (base + 3 < NN) rowptr[base + 3] = excl + v0 + v1 + v2;
    if (tid == 255) blocksum[blockIdx.x] = acc;
}

__global__ __launch_bounds__(128) void scan_block_kernel(int* __restrict__ blocksum)
{
    __shared__ int sm[128];
    const int tid = threadIdx.x;
    const int v = (tid < NBLK) ? blocksum[tid] : 0;
    sm[tid] = v;
    __syncthreads();
    int acc = v;
    for (int off = 1; off < 128; off <<= 1) {
        int other = (tid >= off) ? sm[tid - off] : 0;
        __syncthreads();
        acc += other;
        sm[tid] = acc;
        __syncthreads();
    }
    if (tid < NBLK) blocksum[tid] = acc - v;
}

__global__ __launch_bounds__(256) void finalize_kernel(
    const int* __restrict__ cnt, int* __restrict__ rowptr,
    float* __restrict__ invdeg, const int* __restrict__ blocksum)
{
    int i = blockIdx.x * 256 + threadIdx.x;
    if (i >= NN) return;
    rowptr[i] += blocksum[i / SCAN_CHUNK];
    invdeg[i] = 1.0f / (float)max(cnt[i], 1);
}

// ---------------------------------------------------------------------------
// place: eidx[rowptr[d] + rank] = src — atomic-free. Blocks drain the
// partition matching their physical XCD (s_getreg HW_REG_XCC_ID) first, so
// each partition's 0.8 MB eidx region lives in ONE XCD's L2 (R6's fill
// showed 80 MB HBM writes for 6.4 MB of data from cross-XCD line migration).
// Work-queue chunks + stealing guarantee coverage even if dispatch is weird.
// ---------------------------------------------------------------------------
__global__ __launch_bounds__(256) void place_kernel(
    const uint2* __restrict__ bucket, const int* __restrict__ bcursor,
    const int* __restrict__ rowptr, int* __restrict__ eidx,
    int* __restrict__ wq, int BCAP)
{
    __shared__ int s_chunk;
    const int t  = threadIdx.x;
    const unsigned my = __builtin_amdgcn_s_getreg(63508) & (NPART - 1); // hwreg(XCC_ID=20,0,32)

    for (int pass = 0; pass < NPART; ++pass) {
        const int part = ((int)my + pass) & (NPART - 1);
        const int cntp = bcursor[part];
        const uint2* bp = bucket + (size_t)part * BCAP;
        const int rbase = part * PART_SZ;
        for (;;) {
            __syncthreads();
            if (t == 0) s_chunk = atomicAdd(&wq[part], 1);
            __syncthreads();
            const int base = s_chunk * PCHUNK;
            if (base >= cntp) break;
            const int end = min(base + PCHUNK, cntp);
            for (int i = base + t; i < end; i += 256) {
                const uint2 ent = bp[i];
                const int d    = rbase + (int)(ent.y >> 16);
                const int rank = (int)(ent.y & 0xffffu);
                eidx[rowptr[d] + rank] = (int)ent.x;
            }
        }
    }
}

// ---------------------------------------------------------------------------
// wprep: Wb[n][k] = bf16 of [W1l | W1r] transposed.
// ---------------------------------------------------------------------------
__global__ __launch_bounds__(256) void wprep_kernel(
    const float* __restrict__ W1l, const float* __restrict__ W1r,
    unsigned short* __restrict__ Wb)
{
    const int idx = blockIdx.x * 256 + threadIdx.x;
    if (idx >= 2 * 128 * 128) return;
    const int c   = idx >> 14;
    const int rem = idx & 16383;
    const int n   = rem >> 7;
    const int k   = rem & 127;
    const float* W = c ? W1r : W1l;
    Wb[idx] = f2bf(W[k * 128 + n]);
}

// ---------------------------------------------------------------------------
// pre1 (MFMA): pq = [ x@W1l | x@W1r + b1 ]  (bf16, [NN][256]).
// ---------------------------------------------------------------------------
#define KS 72
__global__ __launch_bounds__(256, 2) void pre1_kernel(
    const float* __restrict__ x, const unsigned short* __restrict__ Wb,
    const float* __restrict__ b1, unsigned short* __restrict__ pq)
{
    __shared__ unsigned short lds[128 * KS + 256 * KS];
    unsigned short* A_s = lds;
    unsigned short* W_s = lds + 128 * KS;

    const int t    = threadIdx.x;
    const int m0   = blockIdx.x * 128;
    const int lane = t & 63;
    const int wave = t >> 6;
    const int lr   = lane & 15;
    const int quad = lane >> 4;
    const int nw0  = wave * 64;

    v4f acc[8][4];
    #pragma unroll
    for (int mt = 0; mt < 8; ++mt)
        #pragma unroll
        for (int nt = 0; nt < 4; ++nt)
            acc[mt][nt] = (v4f){0.f, 0.f, 0.f, 0.f};

    #pragma unroll
    for (int ph = 0; ph < 2; ++ph) {
        const int kh = ph * 64;
        if (ph) __syncthreads();

        {
            const int mi = t & 127;
            const int ko = (t >> 7) * 32;
            const int m  = m0 + mi;
            unsigned short* dp = &A_s[mi * KS + ko];
            if (m < NN) {
                const float4* sp = (const float4*)(x + (size_t)m * F + kh + ko);
                #pragma unroll
                for (int j = 0; j < 8; j += 2) {
                    const float4 f0 = sp[j], f1 = sp[j + 1];
                    uint4 o;
                    o.x = pack2(f0.x, f0.y); o.y = pack2(f0.z, f0.w);
                    o.z = pack2(f1.x, f1.y); o.w = pack2(f1.z, f1.w);
                    *(uint4*)(dp + j * 4) = o;
                }
            } else {
                #pragma unroll
                for (int j = 0; j < 4; ++j)
                    *(uint4*)(dp + j * 8) = make_uint4(0u, 0u, 0u, 0u);
            }
        }
        {
            const unsigned short* sp = Wb + (size_t)t * 128 + kh;
            unsigned short* dp = &W_s[t * KS];
            #pragma unroll
            for (int j = 0; j < 8; ++j)
                *(uint4*)(dp + j * 8) = *(const uint4*)(sp + j * 8);
        }
        __syncthreads();

        #pragma unroll
        for (int ks = 0; ks < 2; ++ks) {
            const int k0 = ks * 32 + quad * 8;
            const v8s b0 = *(const v8s*)&W_s[(nw0 +  0 + lr) * KS + k0];
            const v8s b1v= *(const v8s*)&W_s[(nw0 + 16 + lr) * KS + k0];
            const v8s b2 = *(const v8s*)&W_s[(nw0 + 32 + lr) * KS + k0];
            const v8s b3 = *(const v8s*)&W_s[(nw0 + 48 + lr) * KS + k0];
            #pragma unroll
            for (int mt = 0; mt < 8; ++mt) {
                const v8s a = *(const v8s*)&A_s[(mt * 16 + lr) * KS + k0];
                acc[mt][0] = __builtin_amdgcn_mfma_f32_16x16x32_bf16(a, b0,  acc[mt][0], 0, 0, 0);
                acc[mt][1] = __builtin_amdgcn_mfma_f32_16x16x32_bf16(a, b1v, acc[mt][1], 0, 0, 0);
                acc[mt][2] = __builtin_amdgcn_mfma_f32_16x16x32_bf16(a, b2,  acc[mt][2], 0, 0, 0);
                acc[mt][3] = __builtin_amdgcn_mfma_f32_16x16x32_bf16(a, b3,  acc[mt][3], 0, 0, 0);
            }
        }
        __syncthreads();
    }

    float bias[4];
    #pragma unroll
    for (int nt = 0; nt < 4; ++nt) {
        const int n = nw0 + nt * 16 + lr;
        bias[nt] = (n >= 128) ? b1[n - 128] : 0.0f;
    }

    unsigned short* C_s = lds;
    #pragma unroll
    for (int p = 0; p < 2; ++p) {
        if ((nw0 >> 7) == p) {
            #pragma unroll
            for (int mt = 0; mt < 8; ++mt)
                #pragma unroll
                for (int nt = 0; nt < 4; ++nt) {
                    const int n = (nw0 & 127) + nt * 16 + lr;
                    #pragma unroll
                    for (int r = 0; r < 4; ++r) {
                        const int m = mt * 16 + quad * 4 + r;
                        C_s[m * 136 + n] = f2bf(acc[mt][nt][r] + bias[nt]);
                    }
                }
        }
        __syncthreads();
        {
            const int mi = t & 127;
            const int nh = (t >> 7) * 64;
            const int m  = m0 + mi;
            if (m < NN) {
                unsigned short* dp = pq + (size_t)m * 256 + p * 128 + nh;
                const unsigned short* sp = &C_s[mi * 136 + nh];
                #pragma unroll
                for (int j = 0; j < 8; ++j)
                    *(uint4*)(dp + j * 8) = *(const uint4*)(sp + j * 8);
            }
        }
        __syncthreads();
    }
}

// ---------------------------------------------------------------------------
// agg1: hb[n] = bf16( relu( mean_j p[j] + q[n] ) ).
// ---------------------------------------------------------------------------
__global__ __launch_bounds__(256) void agg1_kernel(
    const unsigned short* __restrict__ pq, const int* __restrict__ eidx,
    const int* __restrict__ rowptr, const int* __restrict__ cnt,
    const float* __restrict__ invdeg, unsigned short* __restrict__ hb)
{
    const int lane = threadIdx.x & 15;
    const int sub  = threadIdx.x >> 4;
    const int n    = blockIdx.x * 16 + sub;
    if (n >= NN) return;
    const int col = lane * 8;

    const int start = rowptr[n];
    const int len   = cnt[n];
    float a0[8] = {0,0,0,0,0,0,0,0};
    float a1[8] = {0,0,0,0,0,0,0,0};
    float a2[8] = {0,0,0,0,0,0,0,0};
    float a3[8] = {0,0,0,0,0,0,0,0};
    int i = 0;
    for (; i + 4 <= len; i += 4) {
        const int s0 = eidx[start + i + 0];
        const int s1 = eidx[start + i + 1];
        const int s2 = eidx[start + i + 2];
        const int s3 = eidx[start + i + 3];
        const uint4 u0 = *(const uint4*)(pq + (size_t)s0 * 256 + col);
        const uint4 u1 = *(const uint4*)(pq + (size_t)s1 * 256 + col);
        const uint4 u2 = *(const uint4*)(pq + (size_t)s2 * 256 + col);
        const uint4 u3 = *(const uint4*)(pq + (size_t)s3 * 256 + col);
        float f0, f1;
        unpack2(u0.x, f0, f1); a0[0] += f0; a0[1] += f1;
        unpack2(u0.y, f0, f1); a0[2] += f0; a0[3] += f1;
        unpack2(u0.z, f0, f1); a0[4] += f0; a0[5] += f1;
        unpack2(u0.w, f0, f1); a0[6] += f0; a0[7] += f1;
        unpack2(u1.x, f0, f1); a1[0] += f0; a1[1] += f1;
        unpack2(u1.y, f0, f1); a1[2] += f0; a1[3] += f1;
        unpack2(u1.z, f0, f1); a1[4] += f0; a1[5] += f1;
        unpack2(u1.w, f0, f1); a1[6] += f0; a1[7] += f1;
        unpack2(u2.x, f0, f1); a2[0] += f0; a2[1] += f1;
        unpack2(u2.y, f0, f1); a2[2] += f0; a2[3] += f1;
        unpack2(u2.z, f0, f1); a2[4] += f0; a2[5] += f1;
        unpack2(u2.w, f0, f1); a2[6] += f0; a2[7] += f1;
        unpack2(u3.x, f0, f1); a3[0] += f0; a3[1] += f1;
        unpack2(u3.y, f0, f1); a3[2] += f0; a3[3] += f1;
        unpack2(u3.z, f0, f1); a3[4] += f0; a3[5] += f1;
        unpack2(u3.w, f0, f1); a3[6] += f0; a3[7] += f1;
    }
    for (; i < len; ++i) {
        const int s = eidx[start + i];
        const uint4 u = *(const uint4*)(pq + (size_t)s * 256 + col);
        float f0, f1;
        unpack2(u.x, f0, f1); a0[0] += f0; a0[1] += f1;
        unpack2(u.y, f0, f1); a0[2] += f0; a0[3] += f1;
        unpack2(u.z, f0, f1); a0[4] += f0; a0[5] += f1;
        unpack2(u.w, f0, f1); a0[6] += f0; a0[7] += f1;
    }
    const float inv = invdeg[n];
    const uint4 uq = *(const uint4*)(pq + (size_t)n * 256 + 128 + col);
    float q[8];
    unpack2(uq.x, q[0], q[1]); unpack2(uq.y, q[2], q[3]);
    unpack2(uq.z, q[4], q[5]); unpack2(uq.w, q[6], q[7]);
    float hv[8];
    #pragma unroll
    for (int j = 0; j < 8; ++j)
        hv[j] = fmaxf((a0[j] + a1[j] + a2[j] + a3[j]) * inv + q[j], 0.0f);
    uint4 o;
    o.x = pack2(hv[0], hv[1]);
    o.y = pack2(hv[2], hv[3]);
    o.z = pack2(hv[4], hv[5]);
    o.w = pack2(hv[6], hv[7]);
    *(uint4*)(hb + (size_t)n * F + col) = o;
}

// ---------------------------------------------------------------------------
// pre2: [z | r] = hb @ [W2l | W2r]; z bf16 [NN][16], r fp32 [NN][16] + bias.
// ---------------------------------------------------------------------------
__global__ __launch_bounds__(256, 2) void pre2_kernel(
    const unsigned short* __restrict__ hb,
    const float* __restrict__ W2l, const float* __restrict__ W2r,
    const float* __restrict__ b2,
    unsigned short* __restrict__ z, float* __restrict__ r)
{
    __shared__ unsigned short A_s[128 * 128];
    __shared__ unsigned short W_s[128 * 32];

    const int t  = threadIdx.x;
    const int m0 = blockIdx.x * 128;

    {
        const int mloc = t & 127;
        const int kc   = (t >> 7) * 64;
        const int m    = m0 + mloc;
        #pragma unroll
        for (int j = 0; j < 8; ++j) {
            const int k = kc + j * 8;
            uint4 u = make_uint4(0u, 0u, 0u, 0u);
            if (m < NN) u = *(const uint4*)(hb + (size_t)m * F + k);
            A_s[(k + 0) * 128 + mloc] = (unsigned short)(u.x & 0xffffu);
            A_s[(k + 1) * 128 + mloc] = (unsigned short)(u.x >> 16);
            A_s[(k + 2) * 128 + mloc] = (unsigned short)(u.y & 0xffffu);
            A_s[(k + 3) * 128 + mloc] = (unsigned short)(u.y >> 16);
            A_s[(k + 4) * 128 + mloc] = (unsigned short)(u.z & 0xffffu);
            A_s[(k + 5) * 128 + mloc] = (unsigned short)(u.z >> 16);
            A_s[(k + 6) * 128 + mloc] = (unsigned short)(u.w & 0xffffu);
            A_s[(k + 7) * 128 + mloc] = (unsigned short)(u.w >> 16);
        }
    }
    #pragma unroll
    for (int rr = 0; rr < 16; ++rr) {
        const int idx = rr * 256 + t;
        const int k = idx >> 5;
        const int c = idx & 31;
        float wv = 0.0f;
        if (c < 16) { if (c < C_OUT) wv = W2l[k * C_OUT + c]; }
        else        { if (c - 16 < C_OUT) wv = W2r[k * C_OUT + (c - 16)]; }
        W_s[k * 32 + c] = f2bf(wv);
    }
    __syncthreads();

    const int mq = t & 31;
    const int nq = t >> 5;
    float acc[4][4];
    #pragma unroll
    for (int i = 0; i < 4; ++i)
        #pragma unroll
        for (int j = 0; j < 4; ++j) acc[i][j] = 0.0f;

    #pragma unroll 4
    for (int k = 0; k < 128; ++k) {
        const uint2 ua = *(const uint2*)&A_s[k * 128 + mq * 4];
        const uint2 uw = *(const uint2*)&W_s[k * 32 + nq * 4];
        float a[4], w[4];
        unpack2(ua.x, a[0], a[1]); unpack2(ua.y, a[2], a[3]);
        unpack2(uw.x, w[0], w[1]); unpack2(uw.y, w[2], w[3]);
        #pragma unroll
        for (int i = 0; i < 4; ++i)
            #pragma unroll
            for (int j = 0; j < 4; ++j)
                acc[i][j] += a[i] * w[j];
    }

    const int c0 = nq * 4;
    #pragma unroll
    for (int i = 0; i < 4; ++i) {
        const int m = m0 + mq * 4 + i;
        if (m < NN) {
            if (nq < 4) {
                uint2 o;
                o.x = pack2(acc[i][0], acc[i][1]);
                o.y = pack2(acc[i][2], acc[i][3]);
                *(uint2*)(z + (size_t)m * ZP + c0) = o;
            } else {
                const int rc = c0 - 16;
                float4 o;
                o.x = acc[i][0] + ((rc + 0 < C_OUT) ? b2[rc + 0] : 0.0f);
                o.y = acc[i][1] + ((rc + 1 < C_OUT) ? b2[rc + 1] : 0.0f);
                o.z = acc[i][2] + ((rc + 2 < C_OUT) ? b2[rc + 2] : 0.0f);
                o.w = acc[i][3] + ((rc + 3 < C_OUT) ? b2[rc + 3] : 0.0f);
                *(float4*)(r + (size_t)m * ZP + rc) = o;
            }
        }
    }
}

// ---------------------------------------------------------------------------
// agg2: out = log_softmax_segments( mean-agg(z) + r ).
// ---------------------------------------------------------------------------
__global__ __launch_bounds__(256) void agg2_kernel(
    const unsigned short* __restrict__ z, const float* __restrict__ r,
    const int* __restrict__ eidx, const int* __restrict__ rowptr,
    const int* __restrict__ cnt, const float* __restrict__ invdeg,
    const int* __restrict__ sf_ptr, float* __restrict__ out)
{
    __shared__ float sm[64][ZP + 1];

    const int lane4 = threadIdx.x & 3;
    const int slot  = threadIdx.x >> 2;
    const int n     = blockIdx.x * 64 + slot;
    const int j4    = lane4 * 4;

    if (n < NN) {
        const int start = rowptr[n];
        const int len   = cnt[n];
        float4 a0 = make_float4(0.f, 0.f, 0.f, 0.f);
        float4 a1 = a0, a2 = a0, a3 = a0;
        int i = 0;
        for (; i + 4 <= len; i += 4) {
            const int s0 = eidx[start + i + 0];
            const int s1 = eidx[start + i + 1];
            const int s2 = eidx[start + i + 2];
            const int s3 = eidx[start + i + 3];
            const uint2 u0 = *(const uint2*)(z + (size_t)s0 * ZP + j4);
            const uint2 u1 = *(const uint2*)(z + (size_t)s1 * ZP + j4);
            const uint2 u2 = *(const uint2*)(z + (size_t)s2 * ZP + j4);
            const uint2 u3 = *(const uint2*)(z + (size_t)s3 * ZP + j4);
            float f0, f1, f2, f3;
            unpack2(u0.x, f0, f1); unpack2(u0.y, f2, f3);
            a0.x += f0; a0.y += f1; a0.z += f2; a0.w += f3;
            unpack2(u1.x, f0, f1); unpack2(u1.y, f2, f3);
            a1.x += f0; a1.y += f1; a1.z += f2; a1.w += f3;
            unpack2(u2.x, f0, f1); unpack2(u2.y, f2, f3);
            a2.x += f0; a2.y += f1; a2.z += f2; a2.w += f3;
            unpack2(u3.x, f0, f1); unpack2(u3.y, f2, f3);
            a3.x += f0; a3.y += f1; a3.z += f2; a3.w += f3;
        }
        for (; i < len; ++i) {
            const int s = eidx[start + i];
            const uint2 u = *(const uint2*)(z + (size_t)s * ZP + j4);
            float f0, f1, f2, f3;
            unpack2(u.x, f0, f1); unpack2(u.y, f2, f3);
            a0.x += f0; a0.y += f1; a0.z += f2; a0.w += f3;
        }
        const float inv = invdeg[n];
        const float4 rv = *(const float4*)(r + (size_t)n * ZP + j4);
        sm[slot][j4 + 0] = (a0.x + a1.x + a2.x + a3.x) * inv + rv.x;
        sm[slot][j4 + 1] = (a0.y + a1.y + a2.y + a3.y) * inv + rv.y;
        sm[slot][j4 + 2] = (a0.z + a1.z + a2.z + a3.z) * inv + rv.z;
        sm[slot][j4 + 3] = (a0.w + a1.w + a2.w + a3.w) * inv + rv.w;
    }
    __syncthreads();

    if (threadIdx.x < 64) {
        const int n2 = blockIdx.x * 64 + threadIdx.x;
        if (n2 < NN) {
            const int sf = *sf_ptr;
            const float* row = sm[threadIdx.x];
            float m = -1e30f;
            for (int c = 0; c < sf; ++c) m = fmaxf(m, row[c]);
            float s = 0.0f;
            for (int c = 0; c < sf; ++c) s += expf(row[c] - m);
            float ls = m + logf(s);
            for (int c = 0; c < sf; ++c)
                out[(long long)n2 * sf + c] = row[c] - ls;
            m = -1e30f;
            for (int c = sf; c < C_OUT; ++c) m = fmaxf(m, row[c]);
            s = 0.0f;
            for (int c = sf; c < C_OUT; ++c) s += expf(row[c] - m);
            ls = m + logf(s);
            const int pt = C_OUT - sf;
            for (int c = sf; c < C_OUT; ++c)
                out[(long long)NN * sf + (long long)n2 * pt + (c - sf)] = row[c] - ls;
        }
    }
}

// ---------------------------------------------------------------------------
extern "C" void kernel_launch(void* const* d_in, const int* in_sizes, int n_in,
                              void* d_out, int out_size, void* d_ws, size_t ws_size,
                              hipStream_t stream)
{
    const float* x   = (const float*)d_in[0];
    const int*   ei  = (const int*)d_in[1];
    const int*   sfp = (const int*)d_in[2];
    const float* W1l = (const float*)d_in[3];
    const float* W1r = (const float*)d_in[4];
    const float* b1  = (const float*)d_in[5];
    const float* W2l = (const float*)d_in[6];
    const float* W2r = (const float*)d_in[7];
    const float* b2  = (const float*)d_in[8];
    float*       out = (float*)d_out;

    const int E  = in_sizes[1] / 2;
    const int E4 = (E + 3) & ~3;
    const int* src = ei;
    const int* dst = ei + E;

    const int BCAP = ((((E / NPART) * 3) / 2 + 1024 + 1) & ~1);   // uint2-aligned

    // ws layout (ints). bucket aliases pq (bucket dead before pre1 writes pq);
    // z aliases pq tail after agg1.
    int*   cnt      = (int*)d_ws;                          // NN
    int*   bcursor  = cnt + NN;                            // 16
    int*   wq       = bcursor + 16;                        // 16
    int*   rowptr   = wq + 16;                             // NN
    float* invdeg   = (float*)(rowptr + NN);               // NN
    int*   blocksum = (int*)(invdeg + NN);                 // 128
    int*   eidx     = blocksum + 128;                      // E4
    unsigned short* Wb = (unsigned short*)(eidx + E4);     // 2*128*128 bf16
    unsigned short* hb = Wb + 2 * 128 * 128;               // NN*F bf16
    unsigned short* pq = hb + (size_t)NN * F;              // NN*256 bf16
    uint2* bucket = (uint2*)pq;                            // alias: 8*BCAP uint2
    unsigned short* z  = pq;                               // alias
    float*          r  = (float*)(pq + (size_t)NN * ZP);   // after z

    // zero cnt + bcursor + wq (contiguous)
    hipMemsetAsync(cnt, 0, (size_t)(NN + 32) * sizeof(int), stream);

    // CSR build: single-pass bin (hist folded in via atomic-rank), scan,
    // atomic-free XCD-affine placement.
    bin_kernel       <<<(E + BIN_BATCH - 1) / BIN_BATCH, 256, 0, stream>>>(
                         src, dst, cnt, bucket, bcursor, BCAP, E);
    scan_local_kernel<<<NBLK, 256, 0, stream>>>(cnt, rowptr, blocksum);
    scan_block_kernel<<<1,    128, 0, stream>>>(blocksum);
    finalize_kernel  <<<(NN + 255) / 256, 256, 0, stream>>>(cnt, rowptr, invdeg, blocksum);
    place_kernel     <<<2048, 256, 0, stream>>>(bucket, bcursor, rowptr, eidx, wq, BCAP);

    // weight prep for MFMA pre1
    wprep_kernel<<<128, 256, 0, stream>>>(W1l, W1r, Wb);

    // layer 1 (commuted): pq = [x@W1l | x@W1r+b1] via MFMA, then gather-mean
    pre1_kernel<<<(NN + 127) / 128, 256, 0, stream>>>(x, Wb, b1, pq);
    agg1_kernel<<<(NN + 15) / 16, 256, 0, stream>>>(pq, eidx, rowptr, cnt, invdeg, hb);

    // layer 2 (commuted): [z|r] = hb@[W2l|W2r], then gather-mean + softmax
    pre2_kernel<<<(NN + 127) / 128, 256, 0, stream>>>(hb, W2l, W2r, b2, z, r);
    agg2_kernel<<<(NN + 63) / 64, 256, 0, stream>>>(z, r, eidx, rowptr, cnt, invdeg,
                                                    sfp, out);
}

// Round 8
// 402.544 us; speedup vs baseline: 1.3458x; 1.3458x over previous
//
#include <hip/hip_runtime.h>
#include <hip/hip_bf16.h>

#define NN 100000
#define F 128
#define C_OUT 14
#define ZP 16
#define SCAN_CHUNK 1024
#define NBLK ((NN + SCAN_CHUNK - 1) / SCAN_CHUNK)   // 98 blocks
#define NPART 8
#define PART_SZ ((NN + NPART - 1) / NPART)          // 12500
#define BIN_BATCH 2048
#define BIN_CAP 640                                  // LDS bucket capacity
#define PCHUNK 1024                                  // place work chunk
#define WQ_STRIDE 16                                 // one counter per 64B line

typedef __attribute__((ext_vector_type(8))) short v8s;   // 8 bf16 (4 VGPRs)
typedef __attribute__((ext_vector_type(4))) float v4f;   // 4 fp32 acc

// ---------------- bf16 helpers (manual, zero API risk) ----------------------
static __device__ __forceinline__ unsigned short f2bf(float f) {
    unsigned int u = __float_as_uint(f);
    unsigned int r = (u + 0x7fffu + ((u >> 16) & 1u)) >> 16;   // RTN-even
    return (unsigned short)r;
}
static __device__ __forceinline__ unsigned int pack2(float a, float b) {
    return (unsigned int)f2bf(a) | ((unsigned int)f2bf(b) << 16);
}
static __device__ __forceinline__ void unpack2(unsigned int u, float& lo, float& hi) {
    lo = __uint_as_float(u << 16);
    hi = __uint_as_float(u & 0xffff0000u);
}

// ---------------------------------------------------------------------------
// bin: single pass over edges. cnt histogram via atomicAdd whose RETURN is
// the edge's rank within its dst. Entries (x=src, y=dloc<<16|rank) staged in
// per-partition LDS buckets, flushed in coalesced chunks.
// ---------------------------------------------------------------------------
__global__ __launch_bounds__(256) void bin_kernel(
    const int* __restrict__ src, const int* __restrict__ dst,
    int* __restrict__ cnt, uint2* __restrict__ bucket,
    int* __restrict__ bcursor, int BCAP, int E)
{
    __shared__ uint2 bs[NPART][BIN_CAP];   // 40 KB
    __shared__ int bcnt[NPART], bbase[NPART];
    const int t  = threadIdx.x;
    const int e0 = blockIdx.x * BIN_BATCH;
    if (t < NPART) bcnt[t] = 0;
    __syncthreads();
    #pragma unroll
    for (int j = 0; j < 8; ++j) {
        const int e = e0 + j * 256 + t;
        if (e < E) {
            const int d = dst[e];
            const int s = src[e];
            const int rank = atomicAdd(&cnt[d], 1);
            const int part = d / PART_SZ;
            const int dloc = d - part * PART_SZ;
            uint2 ent;
            ent.x = (unsigned)s;
            ent.y = ((unsigned)dloc << 16) | ((unsigned)rank & 0xffffu);
            const int slot = atomicAdd(&bcnt[part], 1);
            if (slot < BIN_CAP) bs[part][slot] = ent;
            else {
                const int p = atomicAdd(&bcursor[part], 1);
                bucket[(size_t)part * BCAP + p] = ent;
            }
        }
    }
    __syncthreads();
    if (t < NPART) {
        const int c = min(bcnt[t], BIN_CAP);
        bbase[t] = atomicAdd(&bcursor[t], c);
        bcnt[t] = c;
    }
    __syncthreads();
    for (int part = 0; part < NPART; ++part) {
        const int c    = bcnt[part];
        const int base = bbase[part];
        for (int i = t; i < c; i += 256)
            bucket[(size_t)part * BCAP + base + i] = bs[part][i];
    }
}

__global__ __launch_bounds__(256) void scan_local_kernel(
    const int* __restrict__ cnt, int* __restrict__ rowptr,
    int* __restrict__ blocksum)
{
    __shared__ int sm[256];
    const int tid  = threadIdx.x;
    const int base = blockIdx.x * SCAN_CHUNK + tid * 4;
    int v0 = (base + 0 < NN) ? cnt[base + 0] : 0;
    int v1 = (base + 1 < NN) ? cnt[base + 1] : 0;
    int v2 = (base + 2 < NN) ? cnt[base + 2] : 0;
    int v3 = (base + 3 < NN) ? cnt[base + 3] : 0;
    const int t = v0 + v1 + v2 + v3;
    sm[tid] = t;
    __syncthreads();
    int acc = t;
    for (int off = 1; off < 256; off <<= 1) {
        int other = (tid >= off) ? sm[tid - off] : 0;
        __syncthreads();
        acc += other;
        sm[tid] = acc;
        __syncthreads();
    }
    const int excl = acc - t;
    if (base + 0 < NN) rowptr[base + 0] = excl;
    if (base + 1 < NN) rowptr[base + 1] = excl + v0;
    if (base + 2 < NN) rowptr[base + 2] = excl + v0 + v1;
    if (base + 3 < NN) rowptr[base + 3] = excl + v0 + v1 + v2;
    if (tid == 255) blocksum[blockIdx.x] = acc;
}

__global__ __launch_bounds__(128) void scan_block_kernel(int* __restrict__ blocksum)
{
    __shared__ int sm[128];
    const int tid = threadIdx.x;
    const int v = (tid < NBLK) ? blocksum[tid] : 0;
    sm[tid] = v;
    __syncthreads();
    int acc = v;
    for (int off = 1; off < 128; off <<= 1) {
        int other = (tid >= off) ? sm[tid - off] : 0;
        __syncthreads();
        acc += other;
        sm[tid] = acc;
        __syncthreads();
    }
    if (tid < NBLK) blocksum[tid] = acc - v;
}

__global__ __launch_bounds__(256) void finalize_kernel(
    const int* __restrict__ cnt, int* __restrict__ rowptr,
    float* __restrict__ invdeg, const int* __restrict__ blocksum)
{
    int i = blockIdx.x * 256 + threadIdx.x;
    if (i >= NN) return;
    rowptr[i] += blocksum[i / SCAN_CHUNK];
    invdeg[i] = 1.0f / (float)max(cnt[i], 1);
}

// ---------------------------------------------------------------------------
// place v2: eidx[rowptr[d] + rank] = src — XCD-affine (R7 confirmed: WRITE
// 80->6.8 MB) but WITHOUT the hot-spot work-queue that cost R7 209 us:
//  - each partition counter on its own 64B line (wq[part*16]);
//  - pass 0 (own XCD partition): normal claim loop -> same-XCD atomics only;
//  - steal passes: plain relaxed LOAD guard first; since the counter is
//    monotonic a stale read is conservative (we only skip when all chunks
//    are already CLAIMED; claimed chunks are finished by their owner before
//    it exits, so kernel-end completeness holds).
// ---------------------------------------------------------------------------
__global__ __launch_bounds__(256) void place_kernel(
    const uint2* __restrict__ bucket, const int* __restrict__ bcursor,
    const int* __restrict__ rowptr, int* __restrict__ eidx,
    int* __restrict__ wq, int BCAP)
{
    __shared__ int s_chunk;
    const int t  = threadIdx.x;
    const unsigned my = __builtin_amdgcn_s_getreg(63508) & (NPART - 1); // hwreg(XCC_ID)

    for (int pass = 0; pass < NPART; ++pass) {
        const int part = ((int)my + pass) & (NPART - 1);
        const int cntp = bcursor[part];
        const int nch  = (cntp + PCHUNK - 1) / PCHUNK;
        int* ctr = &wq[part * WQ_STRIDE];
        if (pass > 0) {
            const int seen = __hip_atomic_load(ctr, __ATOMIC_RELAXED,
                                               __HIP_MEMORY_SCOPE_AGENT);
            if (seen >= nch) continue;          // all chunks claimed -> skip
        }
        const uint2* bp = bucket + (size_t)part * BCAP;
        const int rbase = part * PART_SZ;
        for (;;) {
            __syncthreads();
            if (t == 0) s_chunk = atomicAdd(ctr, 1);
            __syncthreads();
            const int base = s_chunk * PCHUNK;
            if (base >= cntp) break;
            const int end = min(base + PCHUNK, cntp);
            for (int i = base + t; i < end; i += 256) {
                const uint2 ent = bp[i];
                const int d    = rbase + (int)(ent.y >> 16);
                const int rank = (int)(ent.y & 0xffffu);
                eidx[rowptr[d] + rank] = (int)ent.x;
            }
        }
    }
}

// ---------------------------------------------------------------------------
// wprep: Wb[n][k] = bf16 of [W1l | W1r] transposed.
// ---------------------------------------------------------------------------
__global__ __launch_bounds__(256) void wprep_kernel(
    const float* __restrict__ W1l, const float* __restrict__ W1r,
    unsigned short* __restrict__ Wb)
{
    const int idx = blockIdx.x * 256 + threadIdx.x;
    if (idx >= 2 * 128 * 128) return;
    const int c   = idx >> 14;
    const int rem = idx & 16383;
    const int n   = rem >> 7;
    const int k   = rem & 127;
    const float* W = c ? W1r : W1l;
    Wb[idx] = f2bf(W[k * 128 + n]);
}

// ---------------------------------------------------------------------------
// pre1 (MFMA): pq = [ x@W1l | x@W1r + b1 ]  (bf16, [NN][256]).
// ---------------------------------------------------------------------------
#define KS 72
__global__ __launch_bounds__(256, 2) void pre1_kernel(
    const float* __restrict__ x, const unsigned short* __restrict__ Wb,
    const float* __restrict__ b1, unsigned short* __restrict__ pq)
{
    __shared__ unsigned short lds[128 * KS + 256 * KS];
    unsigned short* A_s = lds;
    unsigned short* W_s = lds + 128 * KS;

    const int t    = threadIdx.x;
    const int m0   = blockIdx.x * 128;
    const int lane = t & 63;
    const int wave = t >> 6;
    const int lr   = lane & 15;
    const int quad = lane >> 4;
    const int nw0  = wave * 64;

    v4f acc[8][4];
    #pragma unroll
    for (int mt = 0; mt < 8; ++mt)
        #pragma unroll
        for (int nt = 0; nt < 4; ++nt)
            acc[mt][nt] = (v4f){0.f, 0.f, 0.f, 0.f};

    #pragma unroll
    for (int ph = 0; ph < 2; ++ph) {
        const int kh = ph * 64;
        if (ph) __syncthreads();

        {
            const int mi = t & 127;
            const int ko = (t >> 7) * 32;
            const int m  = m0 + mi;
            unsigned short* dp = &A_s[mi * KS + ko];
            if (m < NN) {
                const float4* sp = (const float4*)(x + (size_t)m * F + kh + ko);
                #pragma unroll
                for (int j = 0; j < 8; j += 2) {
                    const float4 f0 = sp[j], f1 = sp[j + 1];
                    uint4 o;
                    o.x = pack2(f0.x, f0.y); o.y = pack2(f0.z, f0.w);
                    o.z = pack2(f1.x, f1.y); o.w = pack2(f1.z, f1.w);
                    *(uint4*)(dp + j * 4) = o;
                }
            } else {
                #pragma unroll
                for (int j = 0; j < 4; ++j)
                    *(uint4*)(dp + j * 8) = make_uint4(0u, 0u, 0u, 0u);
            }
        }
        {
            const unsigned short* sp = Wb + (size_t)t * 128 + kh;
            unsigned short* dp = &W_s[t * KS];
            #pragma unroll
            for (int j = 0; j < 8; ++j)
                *(uint4*)(dp + j * 8) = *(const uint4*)(sp + j * 8);
        }
        __syncthreads();

        #pragma unroll
        for (int ks = 0; ks < 2; ++ks) {
            const int k0 = ks * 32 + quad * 8;
            const v8s b0 = *(const v8s*)&W_s[(nw0 +  0 + lr) * KS + k0];
            const v8s b1v= *(const v8s*)&W_s[(nw0 + 16 + lr) * KS + k0];
            const v8s b2 = *(const v8s*)&W_s[(nw0 + 32 + lr) * KS + k0];
            const v8s b3 = *(const v8s*)&W_s[(nw0 + 48 + lr) * KS + k0];
            #pragma unroll
            for (int mt = 0; mt < 8; ++mt) {
                const v8s a = *(const v8s*)&A_s[(mt * 16 + lr) * KS + k0];
                acc[mt][0] = __builtin_amdgcn_mfma_f32_16x16x32_bf16(a, b0,  acc[mt][0], 0, 0, 0);
                acc[mt][1] = __builtin_amdgcn_mfma_f32_16x16x32_bf16(a, b1v, acc[mt][1], 0, 0, 0);
                acc[mt][2] = __builtin_amdgcn_mfma_f32_16x16x32_bf16(a, b2,  acc[mt][2], 0, 0, 0);
                acc[mt][3] = __builtin_amdgcn_mfma_f32_16x16x32_bf16(a, b3,  acc[mt][3], 0, 0, 0);
            }
        }
        __syncthreads();
    }

    float bias[4];
    #pragma unroll
    for (int nt = 0; nt < 4; ++nt) {
        const int n = nw0 + nt * 16 + lr;
        bias[nt] = (n >= 128) ? b1[n - 128] : 0.0f;
    }

    unsigned short* C_s = lds;
    #pragma unroll
    for (int p = 0; p < 2; ++p) {
        if ((nw0 >> 7) == p) {
            #pragma unroll
            for (int mt = 0; mt < 8; ++mt)
                #pragma unroll
                for (int nt = 0; nt < 4; ++nt) {
                    const int n = (nw0 & 127) + nt * 16 + lr;
                    #pragma unroll
                    for (int r = 0; r < 4; ++r) {
                        const int m = mt * 16 + quad * 4 + r;
                        C_s[m * 136 + n] = f2bf(acc[mt][nt][r] + bias[nt]);
                    }
                }
        }
        __syncthreads();
        {
            const int mi = t & 127;
            const int nh = (t >> 7) * 64;
            const int m  = m0 + mi;
            if (m < NN) {
                unsigned short* dp = pq + (size_t)m * 256 + p * 128 + nh;
                const unsigned short* sp = &C_s[mi * 136 + nh];
                #pragma unroll
                for (int j = 0; j < 8; ++j)
                    *(uint4*)(dp + j * 8) = *(const uint4*)(sp + j * 8);
            }
        }
        __syncthreads();
    }
}

// ---------------------------------------------------------------------------
// agg1: hb[n] = bf16( relu( mean_j p[j] + q[n] ) ).
// ---------------------------------------------------------------------------
__global__ __launch_bounds__(256) void agg1_kernel(
    const unsigned short* __restrict__ pq, const int* __restrict__ eidx,
    const int* __restrict__ rowptr, const int* __restrict__ cnt,
    const float* __restrict__ invdeg, unsigned short* __restrict__ hb)
{
    const int lane = threadIdx.x & 15;
    const int sub  = threadIdx.x >> 4;
    const int n    = blockIdx.x * 16 + sub;
    if (n >= NN) return;
    const int col = lane * 8;

    const int start = rowptr[n];
    const int len   = cnt[n];
    float a0[8] = {0,0,0,0,0,0,0,0};
    float a1[8] = {0,0,0,0,0,0,0,0};
    float a2[8] = {0,0,0,0,0,0,0,0};
    float a3[8] = {0,0,0,0,0,0,0,0};
    int i = 0;
    for (; i + 4 <= len; i += 4) {
        const int s0 = eidx[start + i + 0];
        const int s1 = eidx[start + i + 1];
        const int s2 = eidx[start + i + 2];
        const int s3 = eidx[start + i + 3];
        const uint4 u0 = *(const uint4*)(pq + (size_t)s0 * 256 + col);
        const uint4 u1 = *(const uint4*)(pq + (size_t)s1 * 256 + col);
        const uint4 u2 = *(const uint4*)(pq + (size_t)s2 * 256 + col);
        const uint4 u3 = *(const uint4*)(pq + (size_t)s3 * 256 + col);
        float f0, f1;
        unpack2(u0.x, f0, f1); a0[0] += f0; a0[1] += f1;
        unpack2(u0.y, f0, f1); a0[2] += f0; a0[3] += f1;
        unpack2(u0.z, f0, f1); a0[4] += f0; a0[5] += f1;
        unpack2(u0.w, f0, f1); a0[6] += f0; a0[7] += f1;
        unpack2(u1.x, f0, f1); a1[0] += f0; a1[1] += f1;
        unpack2(u1.y, f0, f1); a1[2] += f0; a1[3] += f1;
        unpack2(u1.z, f0, f1); a1[4] += f0; a1[5] += f1;
        unpack2(u1.w, f0, f1); a1[6] += f0; a1[7] += f1;
        unpack2(u2.x, f0, f1); a2[0] += f0; a2[1] += f1;
        unpack2(u2.y, f0, f1); a2[2] += f0; a2[3] += f1;
        unpack2(u2.z, f0, f1); a2[4] += f0; a2[5] += f1;
        unpack2(u2.w, f0, f1); a2[6] += f0; a2[7] += f1;
        unpack2(u3.x, f0, f1); a3[0] += f0; a3[1] += f1;
        unpack2(u3.y, f0, f1); a3[2] += f0; a3[3] += f1;
        unpack2(u3.z, f0, f1); a3[4] += f0; a3[5] += f1;
        unpack2(u3.w, f0, f1); a3[6] += f0; a3[7] += f1;
    }
    for (; i < len; ++i) {
        const int s = eidx[start + i];
        const uint4 u = *(const uint4*)(pq + (size_t)s * 256 + col);
        float f0, f1;
        unpack2(u.x, f0, f1); a0[0] += f0; a0[1] += f1;
        unpack2(u.y, f0, f1); a0[2] += f0; a0[3] += f1;
        unpack2(u.z, f0, f1); a0[4] += f0; a0[5] += f1;
        unpack2(u.w, f0, f1); a0[6] += f0; a0[7] += f1;
    }
    const float inv = invdeg[n];
    const uint4 uq = *(const uint4*)(pq + (size_t)n * 256 + 128 + col);
    float q[8];
    unpack2(uq.x, q[0], q[1]); unpack2(uq.y, q[2], q[3]);
    unpack2(uq.z, q[4], q[5]); unpack2(uq.w, q[6], q[7]);
    float hv[8];
    #pragma unroll
    for (int j = 0; j < 8; ++j)
        hv[j] = fmaxf((a0[j] + a1[j] + a2[j] + a3[j]) * inv + q[j], 0.0f);
    uint4 o;
    o.x = pack2(hv[0], hv[1]);
    o.y = pack2(hv[2], hv[3]);
    o.z = pack2(hv[4], hv[5]);
    o.w = pack2(hv[6], hv[7]);
    *(uint4*)(hb + (size_t)n * F + col) = o;
}

// ---------------------------------------------------------------------------
// pre2: [z | r] = hb @ [W2l | W2r]; z bf16 [NN][16], r fp32 [NN][16] + bias.
// ---------------------------------------------------------------------------
__global__ __launch_bounds__(256, 2) void pre2_kernel(
    const unsigned short* __restrict__ hb,
    const float* __restrict__ W2l, const float* __restrict__ W2r,
    const float* __restrict__ b2,
    unsigned short* __restrict__ z, float* __restrict__ r)
{
    __shared__ unsigned short A_s[128 * 128];
    __shared__ unsigned short W_s[128 * 32];

    const int t  = threadIdx.x;
    const int m0 = blockIdx.x * 128;

    {
        const int mloc = t & 127;
        const int kc   = (t >> 7) * 64;
        const int m    = m0 + mloc;
        #pragma unroll
        for (int j = 0; j < 8; ++j) {
            const int k = kc + j * 8;
            uint4 u = make_uint4(0u, 0u, 0u, 0u);
            if (m < NN) u = *(const uint4*)(hb + (size_t)m * F + k);
            A_s[(k + 0) * 128 + mloc] = (unsigned short)(u.x & 0xffffu);
            A_s[(k + 1) * 128 + mloc] = (unsigned short)(u.x >> 16);
            A_s[(k + 2) * 128 + mloc] = (unsigned short)(u.y & 0xffffu);
            A_s[(k + 3) * 128 + mloc] = (unsigned short)(u.y >> 16);
            A_s[(k + 4) * 128 + mloc] = (unsigned short)(u.z & 0xffffu);
            A_s[(k + 5) * 128 + mloc] = (unsigned short)(u.z >> 16);
            A_s[(k + 6) * 128 + mloc] = (unsigned short)(u.w & 0xffffu);
            A_s[(k + 7) * 128 + mloc] = (unsigned short)(u.w >> 16);
        }
    }
    #pragma unroll
    for (int rr = 0; rr < 16; ++rr) {
        const int idx = rr * 256 + t;
        const int k = idx >> 5;
        const int c = idx & 31;
        float wv = 0.0f;
        if (c < 16) { if (c < C_OUT) wv = W2l[k * C_OUT + c]; }
        else        { if (c - 16 < C_OUT) wv = W2r[k * C_OUT + (c - 16)]; }
        W_s[k * 32 + c] = f2bf(wv);
    }
    __syncthreads();

    const int mq = t & 31;
    const int nq = t >> 5;
    float acc[4][4];
    #pragma unroll
    for (int i = 0; i < 4; ++i)
        #pragma unroll
        for (int j = 0; j < 4; ++j) acc[i][j] = 0.0f;

    #pragma unroll 4
    for (int k = 0; k < 128; ++k) {
        const uint2 ua = *(const uint2*)&A_s[k * 128 + mq * 4];
        const uint2 uw = *(const uint2*)&W_s[k * 32 + nq * 4];
        float a[4], w[4];
        unpack2(ua.x, a[0], a[1]); unpack2(ua.y, a[2], a[3]);
        unpack2(uw.x, w[0], w[1]); unpack2(uw.y, w[2], w[3]);
        #pragma unroll
        for (int i = 0; i < 4; ++i)
            #pragma unroll
            for (int j = 0; j < 4; ++j)
                acc[i][j] += a[i] * w[j];
    }

    const int c0 = nq * 4;
    #pragma unroll
    for (int i = 0; i < 4; ++i) {
        const int m = m0 + mq * 4 + i;
        if (m < NN) {
            if (nq < 4) {
                uint2 o;
                o.x = pack2(acc[i][0], acc[i][1]);
                o.y = pack2(acc[i][2], acc[i][3]);
                *(uint2*)(z + (size_t)m * ZP + c0) = o;
            } else {
                const int rc = c0 - 16;
                float4 o;
                o.x = acc[i][0] + ((rc + 0 < C_OUT) ? b2[rc + 0] : 0.0f);
                o.y = acc[i][1] + ((rc + 1 < C_OUT) ? b2[rc + 1] : 0.0f);
                o.z = acc[i][2] + ((rc + 2 < C_OUT) ? b2[rc + 2] : 0.0f);
                o.w = acc[i][3] + ((rc + 3 < C_OUT) ? b2[rc + 3] : 0.0f);
                *(float4*)(r + (size_t)m * ZP + rc) = o;
            }
        }
    }
}

// ---------------------------------------------------------------------------
// agg2: out = log_softmax_segments( mean-agg(z) + r ).
// ---------------------------------------------------------------------------
__global__ __launch_bounds__(256) void agg2_kernel(
    const unsigned short* __restrict__ z, const float* __restrict__ r,
    const int* __restrict__ eidx, const int* __restrict__ rowptr,
    const int* __restrict__ cnt, const float* __restrict__ invdeg,
    const int* __restrict__ sf_ptr, float* __restrict__ out)
{
    __shared__ float sm[64][ZP + 1];

    const int lane4 = threadIdx.x & 3;
    const int slot  = threadIdx.x >> 2;
    const int n     = blockIdx.x * 64 + slot;
    const int j4    = lane4 * 4;

    if (n < NN) {
        const int start = rowptr[n];
        const int len   = cnt[n];
        float4 a0 = make_float4(0.f, 0.f, 0.f, 0.f);
        float4 a1 = a0, a2 = a0, a3 = a0;
        int i = 0;
        for (; i + 4 <= len; i += 4) {
            const int s0 = eidx[start + i + 0];
            const int s1 = eidx[start + i + 1];
            const int s2 = eidx[start + i + 2];
            const int s3 = eidx[start + i + 3];
            const uint2 u0 = *(const uint2*)(z + (size_t)s0 * ZP + j4);
            const uint2 u1 = *(const uint2*)(z + (size_t)s1 * ZP + j4);
            const uint2 u2 = *(const uint2*)(z + (size_t)s2 * ZP + j4);
            const uint2 u3 = *(const uint2*)(z + (size_t)s3 * ZP + j4);
            float f0, f1, f2, f3;
            unpack2(u0.x, f0, f1); unpack2(u0.y, f2, f3);
            a0.x += f0; a0.y += f1; a0.z += f2; a0.w += f3;
            unpack2(u1.x, f0, f1); unpack2(u1.y, f2, f3);
            a1.x += f0; a1.y += f1; a1.z += f2; a1.w += f3;
            unpack2(u2.x, f0, f1); unpack2(u2.y, f2, f3);
            a2.x += f0; a2.y += f1; a2.z += f2; a2.w += f3;
            unpack2(u3.x, f0, f1); unpack2(u3.y, f2, f3);
            a3.x += f0; a3.y += f1; a3.z += f2; a3.w += f3;
        }
        for (; i < len; ++i) {
            const int s = eidx[start + i];
            const uint2 u = *(const uint2*)(z + (size_t)s * ZP + j4);
            float f0, f1, f2, f3;
            unpack2(u.x, f0, f1); unpack2(u.y, f2, f3);
            a0.x += f0; a0.y += f1; a0.z += f2; a0.w += f3;
        }
        const float inv = invdeg[n];
        const float4 rv = *(const float4*)(r + (size_t)n * ZP + j4);
        sm[slot][j4 + 0] = (a0.x + a1.x + a2.x + a3.x) * inv + rv.x;
        sm[slot][j4 + 1] = (a0.y + a1.y + a2.y + a3.y) * inv + rv.y;
        sm[slot][j4 + 2] = (a0.z + a1.z + a2.z + a3.z) * inv + rv.z;
        sm[slot][j4 + 3] = (a0.w + a1.w + a2.w + a3.w) * inv + rv.w;
    }
    __syncthreads();

    if (threadIdx.x < 64) {
        const int n2 = blockIdx.x * 64 + threadIdx.x;
        if (n2 < NN) {
            const int sf = *sf_ptr;
            const float* row = sm[threadIdx.x];
            float m = -1e30f;
            for (int c = 0; c < sf; ++c) m = fmaxf(m, row[c]);
            float s = 0.0f;
            for (int c = 0; c < sf; ++c) s += expf(row[c] - m);
            float ls = m + logf(s);
            for (int c = 0; c < sf; ++c)
                out[(long long)n2 * sf + c] = row[c] - ls;
            m = -1e30f;
            for (int c = sf; c < C_OUT; ++c) m = fmaxf(m, row[c]);
            s = 0.0f;
            for (int c = sf; c < C_OUT; ++c) s += expf(row[c] - m);
            ls = m + logf(s);
            const int pt = C_OUT - sf;
            for (int c = sf; c < C_OUT; ++c)
                out[(long long)NN * sf + (long long)n2 * pt + (c - sf)] = row[c] - ls;
        }
    }
}

// ---------------------------------------------------------------------------
extern "C" void kernel_launch(void* const* d_in, const int* in_sizes, int n_in,
                              void* d_out, int out_size, void* d_ws, size_t ws_size,
                              hipStream_t stream)
{
    const float* x   = (const float*)d_in[0];
    const int*   ei  = (const int*)d_in[1];
    const int*   sfp = (const int*)d_in[2];
    const float* W1l = (const float*)d_in[3];
    const float* W1r = (const float*)d_in[4];
    const float* b1  = (const float*)d_in[5];
    const float* W2l = (const float*)d_in[6];
    const float* W2r = (const float*)d_in[7];
    const float* b2  = (const float*)d_in[8];
    float*       out = (float*)d_out;

    const int E  = in_sizes[1] / 2;
    const int E4 = (E + 3) & ~3;
    const int* src = ei;
    const int* dst = ei + E;

    const int BCAP = ((((E / NPART) * 3) / 2 + 1024 + 1) & ~1);   // uint2-aligned

    // ws layout (ints). bucket aliases pq; z aliases pq after agg1.
    int*   cnt      = (int*)d_ws;                          // NN
    int*   bcursor  = cnt + NN;                            // 16
    int*   wq       = bcursor + 16;                        // NPART*WQ_STRIDE = 128
    int*   rowptr   = wq + NPART * WQ_STRIDE;              // NN
    float* invdeg   = (float*)(rowptr + NN);               // NN
    int*   blocksum = (int*)(invdeg + NN);                 // 128
    int*   eidx     = blocksum + 128;                      // E4
    unsigned short* Wb = (unsigned short*)(eidx + E4);     // 2*128*128 bf16
    unsigned short* hb = Wb + 2 * 128 * 128;               // NN*F bf16
    unsigned short* pq = hb + (size_t)NN * F;              // NN*256 bf16
    uint2* bucket = (uint2*)pq;                            // alias: 8*BCAP uint2
    unsigned short* z  = pq;                               // alias
    float*          r  = (float*)(pq + (size_t)NN * ZP);   // after z

    // zero cnt + bcursor + wq (contiguous)
    hipMemsetAsync(cnt, 0, (size_t)(NN + 16 + NPART * WQ_STRIDE) * sizeof(int), stream);

    // CSR build: single-pass bin, scan, XCD-affine low-contention placement.
    bin_kernel       <<<(E + BIN_BATCH - 1) / BIN_BATCH, 256, 0, stream>>>(
                         src, dst, cnt, bucket, bcursor, BCAP, E);
    scan_local_kernel<<<NBLK, 256, 0, stream>>>(cnt, rowptr, blocksum);
    scan_block_kernel<<<1,    128, 0, stream>>>(blocksum);
    finalize_kernel  <<<(NN + 255) / 256, 256, 0, stream>>>(cnt, rowptr, invdeg, blocksum);
    place_kernel     <<<1024, 256, 0, stream>>>(bucket, bcursor, rowptr, eidx, wq, BCAP);

    // weight prep for MFMA pre1
    wprep_kernel<<<128, 256, 0, stream>>>(W1l, W1r, Wb);

    // layer 1 (commuted): pq = [x@W1l | x@W1r+b1] via MFMA, then gather-mean
    pre1_kernel<<<(NN + 127) / 128, 256, 0, stream>>>(x, Wb, b1, pq);
    agg1_kernel<<<(NN + 15) / 16, 256, 0, stream>>>(pq, eidx, rowptr, cnt, invdeg, hb);

    // layer 2 (commuted): [z|r] = hb@[W2l|W2r], then gather-mean + softmax
    pre2_kernel<<<(NN + 127) / 128, 256, 0, stream>>>(hb, W2l, W2r, b2, z, r);
    agg2_kernel<<<(NN + 63) / 64, 256, 0, stream>>>(z, r, eidx, rowptr, cnt, invdeg,
                                                    sfp, out);
}